// Round 2
// baseline (448.043 us; speedup 1.0000x reference)
//
#include <hip/hip_runtime.h>
#include <hip/hip_bf16.h>
#include <stdint.h>

typedef __bf16 bf16_t;
typedef __bf16 bf16x8 __attribute__((ext_vector_type(8)));
typedef float f32x4 __attribute__((ext_vector_type(4)));

#define Edim 2048
#define Cdim 64
#define Fdim 18
#define Pdim 1024
#define Ntok (Fdim * Pdim)   // 18432

// convert 8 consecutive f32 at p (16B-aligned) to a bf16x8 fragment
__device__ __forceinline__ bf16x8 cvt8(const float* __restrict__ p) {
    float4 lo = *(const float4*)p;
    float4 hi = *(const float4*)(p + 4);
    bf16x8 r;
    r[0] = (bf16_t)lo.x; r[1] = (bf16_t)lo.y; r[2] = (bf16_t)lo.z; r[3] = (bf16_t)lo.w;
    r[4] = (bf16_t)hi.x; r[5] = (bf16_t)hi.y; r[6] = (bf16_t)hi.z; r[7] = (bf16_t)hi.w;
    return r;
}

// ---------------------------------------------------------------------------
// small GEMM: out[64,2048] = scale * ( Ws[64,2048] @ Bb[2048,2048] )   (f32 in)
// Contraction over Bb's ROW index -> stage a 32k x 64n Bb tile into LDS
// transposed as bf16 ([n][k], stride 40 elems = 80 B, 16B-aligned b128 reads).
// grid = 32 (n-tiles of 64), block = 256 (4 waves partition M=64).
// Writes f32 (out_f) and/or bf16 (out_b).
// ---------------------------------------------------------------------------
__global__ __launch_bounds__(256) void small_gemm_kernel(
    const float* __restrict__ Ws, const float* __restrict__ Bb,
    float* __restrict__ out_f, bf16_t* __restrict__ out_b, float scale)
{
    __shared__ __align__(16) bf16_t Bt[64 * 40];

    const int tid  = threadIdx.x;
    const int wave = tid >> 6;
    const int lane = tid & 63;
    const int l15  = lane & 15;
    const int koct = lane >> 4;          // 0..3
    const int n0   = blockIdx.x * 64;

    // staging role: thread covers (k = koct_s*8 + j, n = n_s)
    const int n_s    = tid & 63;
    const int koct_s = tid >> 6;         // 0..3

    f32x4 acc[4] = {};

    for (int k0 = 0; k0 < Edim; k0 += 32) {
        // gather 8 strided (coalesced-across-lanes) f32 of Bb, convert to bf16
        bf16x8 v;
        const float* src = Bb + (size_t)(k0 + koct_s * 8) * Edim + n0 + n_s;
        #pragma unroll
        for (int j = 0; j < 8; ++j) v[j] = (bf16_t)src[(size_t)j * Edim];

        __syncthreads();   // previous iteration's fragment reads done
        *(bf16x8*)&Bt[n_s * 40 + koct_s * 8] = v;
        __syncthreads();   // staging visible

        // A fragment straight from global (k-contiguous f32 -> bf16)
        bf16x8 a = cvt8(Ws + (size_t)(wave * 16 + l15) * Edim + k0 + koct * 8);
        #pragma unroll
        for (int t = 0; t < 4; ++t) {
            bf16x8 b = *(const bf16x8*)&Bt[(t * 16 + l15) * 40 + koct * 8];
            acc[t] = __builtin_amdgcn_mfma_f32_16x16x32_bf16(a, b, acc[t], 0, 0, 0);
        }
    }

    #pragma unroll
    for (int t = 0; t < 4; ++t) {
        #pragma unroll
        for (int r = 0; r < 4; ++r) {
            int m = wave * 16 + koct * 4 + r;     // C/D row = (lane>>4)*4 + reg
            int n = n0 + t * 16 + l15;            // C/D col = lane&15
            float val = scale * acc[t][r];
            if (out_f) out_f[(size_t)m * Edim + n] = val;
            if (out_b) out_b[(size_t)m * Edim + n] = (bf16_t)val;
        }
    }
}

// ---------------------------------------------------------------------------
// b_eff[c] = 0.75 * ( A[c,:]·bv + Wmp[c,:]·bo ) + bmp[c]      (all f32)
// grid = 64 (one block per c), block = 256; each thread handles one 8-elem octet.
// ---------------------------------------------------------------------------
__global__ __launch_bounds__(256) void bias_kernel(
    const float* __restrict__ A, const float* __restrict__ Wmp,
    const float* __restrict__ bv, const float* __restrict__ bo,
    const float* __restrict__ bmp, float* __restrict__ b_eff)
{
    const int c   = blockIdx.x;
    const int tid = threadIdx.x;

    const float* ap = A   + (size_t)c * Edim + tid * 8;
    const float* wp = Wmp + (size_t)c * Edim + tid * 8;
    const float* bvp = bv + tid * 8;
    const float* bop = bo + tid * 8;

    float s = 0.f;
    #pragma unroll
    for (int j = 0; j < 8; ++j)
        s += ap[j] * bvp[j] + wp[j] * bop[j];

    #pragma unroll
    for (int off = 32; off > 0; off >>= 1) s += __shfl_down(s, off);

    __shared__ float red[4];
    if ((tid & 63) == 0) red[tid >> 6] = s;
    __syncthreads();
    if (tid == 0)
        b_eff[c] = 0.75f * (red[0] + red[1] + red[2] + red[3]) + bmp[c];
}

// ---------------------------------------------------------------------------
// main GEMM: out[(p*F+f)*64 + c] = X[n,:]·Weff[c,:] + b_eff[c],  n = f*P+p
// X = emb flat [18432, 2048] f32 (converted to bf16 in-flight);
// Weff row-major [64, 2048] bf16 (0.75 pre-folded), L2-resident.
// grid = 288 (64 rows/block), block = 256 (4 waves x 16 rows). Output f32.
// ---------------------------------------------------------------------------
__global__ __launch_bounds__(256) void main_gemm_kernel(
    const float* __restrict__ X, const bf16_t* __restrict__ Weff,
    const float* __restrict__ b_eff, float* __restrict__ out)
{
    const int tid  = threadIdx.x;
    const int wave = tid >> 6;
    const int lane = tid & 63;
    const int l15  = lane & 15;
    const int koct = lane >> 4;

    const int rowa = blockIdx.x * 64 + wave * 16 + l15;   // A-frag row
    const float* xp = X + (size_t)rowa * Edim;

    f32x4 acc[4] = {};

    #pragma unroll 2
    for (int k0 = 0; k0 < Edim; k0 += 32) {
        bf16x8 a = cvt8(xp + k0 + koct * 8);
        #pragma unroll
        for (int t = 0; t < 4; ++t) {
            bf16x8 b = *(const bf16x8*)(Weff + (size_t)(t * 16 + l15) * Edim + k0 + koct * 8);
            acc[t] = __builtin_amdgcn_mfma_f32_16x16x32_bf16(a, b, acc[t], 0, 0, 0);
        }
    }

    const int mbase = blockIdx.x * 64 + wave * 16 + koct * 4;  // C/D row base
    #pragma unroll
    for (int t = 0; t < 4; ++t) {
        const int c  = t * 16 + l15;
        const float be = b_eff[c];
        #pragma unroll
        for (int r = 0; r < 4; ++r) {
            const int m = mbase + r;
            const int f = m >> 10;          // n / 1024
            const int p = m & 1023;         // n % 1024
            out[(size_t)(p * Fdim + f) * Cdim + c] = acc[t][r] + be;
        }
    }
}

// ---------------------------------------------------------------------------
extern "C" void kernel_launch(void* const* d_in, const int* in_sizes, int n_in,
                              void* d_out, int out_size, void* d_ws, size_t ws_size,
                              hipStream_t stream)
{
    // setup_inputs order: emb, Wq, Wk, Wv, bq, bk, bv, Wo, bo, Wmp, bmp (all f32)
    const float* emb = (const float*)d_in[0];
    const float* Wv  = (const float*)d_in[3];
    const float* bv  = (const float*)d_in[6];
    const float* Wo  = (const float*)d_in[7];
    const float* bo  = (const float*)d_in[8];
    const float* Wmp = (const float*)d_in[9];
    const float* bmp = (const float*)d_in[10];

    float*  A     = (float*)d_ws;                          // [64,2048] f32 (512 KB)
    bf16_t* Weffb = (bf16_t*)(A + (size_t)Cdim * Edim);    // [64,2048] bf16 (256 KB)
    float*  beff  = (float*)(Weffb + (size_t)Cdim * Edim); // [64] f32

    float* out = (float*)d_out;

    // A = Wmp @ Wo   (f32 out)
    small_gemm_kernel<<<32, 256, 0, stream>>>(Wmp, Wo, A, nullptr, 1.0f);
    // b_eff = 0.75*(A·bv + Wmp·bo) + bmp
    bias_kernel<<<64, 256, 0, stream>>>(A, Wmp, bv, bo, bmp, beff);
    // Weff = 0.75 * (A @ Wv)   (bf16 out)
    small_gemm_kernel<<<32, 256, 0, stream>>>(A, Wv, nullptr, Weffb, 0.75f);
    // out = X @ Weff^T + b_eff  (+ output row permutation)
    main_gemm_kernel<<<Ntok / 64, 256, 0, stream>>>(emb, Weffb, beff, out);
}

// Round 3
// 308.345 us; speedup vs baseline: 1.4531x; 1.4531x over previous
//
#include <hip/hip_runtime.h>
#include <hip/hip_bf16.h>
#include <stdint.h>

typedef __bf16 bf16_t;
typedef __bf16 bf16x8 __attribute__((ext_vector_type(8)));
typedef float f32x4 __attribute__((ext_vector_type(4)));

#define Edim 2048
#define Cdim 64
#define Fdim 18
#define Pdim 1024
#define Ntok (Fdim * Pdim)   // 18432

// convert 8 consecutive f32 at p (16B-aligned) to a bf16x8 fragment
__device__ __forceinline__ bf16x8 cvt8(const float* __restrict__ p) {
    float4 lo = *(const float4*)p;
    float4 hi = *(const float4*)(p + 4);
    bf16x8 r;
    r[0] = (bf16_t)lo.x; r[1] = (bf16_t)lo.y; r[2] = (bf16_t)lo.z; r[3] = (bf16_t)lo.w;
    r[4] = (bf16_t)hi.x; r[5] = (bf16_t)hi.y; r[6] = (bf16_t)hi.z; r[7] = (bf16_t)hi.w;
    return r;
}

// ---------------------------------------------------------------------------
// split-K small GEMM: outAcc[64,2048](f32, pre-zeroed) += Am[64,2048] @ Bm[2048,2048]
// grid = (32 n-tiles, 8 k-chunks), block = 256 (4 waves partition M=64).
// No LDS, no barriers: B fragments gathered per-lane (coalesced across lanes,
// shared across waves via L1); 8 k-iterations per block; atomicAdd epilogue.
// ---------------------------------------------------------------------------
__global__ __launch_bounds__(256) void splitk_gemm_kernel(
    const float* __restrict__ Am, const float* __restrict__ Bm,
    float* __restrict__ outAcc)
{
    const int tid  = threadIdx.x;
    const int wave = tid >> 6;
    const int lane = tid & 63;
    const int l15  = lane & 15;
    const int koct = lane >> 4;
    const int n0   = blockIdx.x * 64;
    const int kb   = blockIdx.y * 256;

    f32x4 acc[4] = {};

    for (int k0 = kb; k0 < kb + 256; k0 += 32) {
        bf16x8 a = cvt8(Am + (size_t)(wave * 16 + l15) * Edim + k0 + koct * 8);
        #pragma unroll
        for (int t = 0; t < 4; ++t) {
            const float* src = Bm + (size_t)(k0 + koct * 8) * Edim + n0 + t * 16 + l15;
            bf16x8 b;
            #pragma unroll
            for (int j = 0; j < 8; ++j) b[j] = (bf16_t)src[(size_t)j * Edim];
            acc[t] = __builtin_amdgcn_mfma_f32_16x16x32_bf16(a, b, acc[t], 0, 0, 0);
        }
    }

    #pragma unroll
    for (int t = 0; t < 4; ++t) {
        #pragma unroll
        for (int r = 0; r < 4; ++r) {
            int m = wave * 16 + koct * 4 + r;   // C/D row = (lane>>4)*4 + reg
            int n = n0 + t * 16 + l15;          // C/D col = lane&15
            atomicAdd(&outAcc[(size_t)m * Edim + n], acc[t][r]);
        }
    }
}

// ---------------------------------------------------------------------------
// u[r] = Wo[r,:]·bv + bo[r]   (row-contiguous matvec, grid 512 x 4 rows/block)
// ---------------------------------------------------------------------------
__global__ __launch_bounds__(256) void matvec_kernel(
    const float* __restrict__ Wo, const float* __restrict__ bv,
    const float* __restrict__ bo, float* __restrict__ u)
{
    const int tid  = threadIdx.x;
    const int wave = tid >> 6;
    const int lane = tid & 63;
    const int r    = blockIdx.x * 4 + wave;

    const float* wp = Wo + (size_t)r * Edim;
    float s = 0.f;
    #pragma unroll
    for (int c = 0; c < 8; ++c) {
        float4 w4 = *(const float4*)(wp + c * 256 + lane * 4);
        float4 b4 = *(const float4*)(bv + c * 256 + lane * 4);
        s += w4.x * b4.x + w4.y * b4.y + w4.z * b4.z + w4.w * b4.w;
    }
    #pragma unroll
    for (int off = 32; off > 0; off >>= 1) s += __shfl_down(s, off);
    if (lane == 0) u[r] = s + bo[r];
}

// ---------------------------------------------------------------------------
// b_eff[c] = 0.75 * Wmp[c,:]·u + bmp[c]    (grid 64, block 256)
// ---------------------------------------------------------------------------
__global__ __launch_bounds__(256) void bias2_kernel(
    const float* __restrict__ Wmp, const float* __restrict__ u,
    const float* __restrict__ bmp, float* __restrict__ b_eff)
{
    const int c   = blockIdx.x;
    const int tid = threadIdx.x;

    const float* wp = Wmp + (size_t)c * Edim + tid * 8;
    const float* up = u + tid * 8;
    float s = 0.f;
    #pragma unroll
    for (int j = 0; j < 8; ++j) s += wp[j] * up[j];

    #pragma unroll
    for (int off = 32; off > 0; off >>= 1) s += __shfl_down(s, off);

    __shared__ float red[4];
    if ((tid & 63) == 0) red[tid >> 6] = s;
    __syncthreads();
    if (tid == 0)
        b_eff[c] = 0.75f * (red[0] + red[1] + red[2] + red[3]) + bmp[c];
}

// ---------------------------------------------------------------------------
// Weffb = bf16( 0.75 * Weff_f32 )   (131072 elems; grid 64 x 256 x 8)
// ---------------------------------------------------------------------------
__global__ __launch_bounds__(256) void convert_kernel(
    const float* __restrict__ Wf, bf16_t* __restrict__ Wb)
{
    const int i = (blockIdx.x * 256 + threadIdx.x) * 8;
    float4 lo = *(const float4*)(Wf + i);
    float4 hi = *(const float4*)(Wf + i + 4);
    bf16x8 r;
    r[0] = (bf16_t)(0.75f * lo.x); r[1] = (bf16_t)(0.75f * lo.y);
    r[2] = (bf16_t)(0.75f * lo.z); r[3] = (bf16_t)(0.75f * lo.w);
    r[4] = (bf16_t)(0.75f * hi.x); r[5] = (bf16_t)(0.75f * hi.y);
    r[6] = (bf16_t)(0.75f * hi.z); r[7] = (bf16_t)(0.75f * hi.w);
    *(bf16x8*)(Wb + i) = r;
}

// ---------------------------------------------------------------------------
// main GEMM, split-K x4 per block: out[(p*F+f)*64+c] = X[n,:]·Weff[c,:] + b_eff[c]
// grid = 1152 (16 rows/block), block = 256: wave w handles K-quarter w*512..+512
// of the same 16-row M-tile; LDS reduce; wave 0 does the epilogue.
// ---------------------------------------------------------------------------
__global__ __launch_bounds__(256) void main_gemm_kernel(
    const float* __restrict__ X, const bf16_t* __restrict__ Weff,
    const float* __restrict__ b_eff, float* __restrict__ out)
{
    __shared__ float red[3 * 64 * 17];   // 3 waves x 64 lanes x 16 (+1 pad)

    const int tid  = threadIdx.x;
    const int wave = tid >> 6;
    const int lane = tid & 63;
    const int l15  = lane & 15;
    const int koct = lane >> 4;

    const int rowa = blockIdx.x * 16 + l15;       // A-frag row
    const float* xp = X + (size_t)rowa * Edim;
    const int kbase = wave * 512;

    f32x4 acc[4] = {};

    #pragma unroll 2
    for (int k0 = kbase; k0 < kbase + 512; k0 += 32) {
        bf16x8 a = cvt8(xp + k0 + koct * 8);
        #pragma unroll
        for (int t = 0; t < 4; ++t) {
            bf16x8 b = *(const bf16x8*)(Weff + (size_t)(t * 16 + l15) * Edim + k0 + koct * 8);
            acc[t] = __builtin_amdgcn_mfma_f32_16x16x32_bf16(a, b, acc[t], 0, 0, 0);
        }
    }

    if (wave != 0) {
        float* dst = &red[(wave - 1) * 1088 + lane * 17];
        #pragma unroll
        for (int t = 0; t < 4; ++t)
            #pragma unroll
            for (int r = 0; r < 4; ++r) dst[t * 4 + r] = acc[t][r];
    }
    __syncthreads();
    if (wave == 0) {
        #pragma unroll
        for (int w = 0; w < 3; ++w) {
            const float* srcp = &red[w * 1088 + lane * 17];
            #pragma unroll
            for (int t = 0; t < 4; ++t)
                #pragma unroll
                for (int r = 0; r < 4; ++r) acc[t][r] += srcp[t * 4 + r];
        }
        const int mbase = blockIdx.x * 16 + koct * 4;   // C/D row base
        #pragma unroll
        for (int t = 0; t < 4; ++t) {
            const int c  = t * 16 + l15;
            const float be = b_eff[c];
            #pragma unroll
            for (int r = 0; r < 4; ++r) {
                const int m = mbase + r;
                const int f = m >> 10;          // n / 1024
                const int p = m & 1023;         // n % 1024
                out[(size_t)(p * Fdim + f) * Cdim + c] = acc[t][r] + be;
            }
        }
    }
}

// ---------------------------------------------------------------------------
extern "C" void kernel_launch(void* const* d_in, const int* in_sizes, int n_in,
                              void* d_out, int out_size, void* d_ws, size_t ws_size,
                              hipStream_t stream)
{
    // setup_inputs order: emb, Wq, Wk, Wv, bq, bk, bv, Wo, bo, Wmp, bmp (all f32)
    const float* emb = (const float*)d_in[0];
    const float* Wv  = (const float*)d_in[3];
    const float* bv  = (const float*)d_in[6];
    const float* Wo  = (const float*)d_in[7];
    const float* bo  = (const float*)d_in[8];
    const float* Wmp = (const float*)d_in[9];
    const float* bmp = (const float*)d_in[10];

    float*  A_f32 = (float*)d_ws;                              // [64,2048] f32 (512 KB)
    float*  W_f32 = A_f32 + (size_t)Cdim * Edim;               // [64,2048] f32 (512 KB)
    bf16_t* Weffb = (bf16_t*)(W_f32 + (size_t)Cdim * Edim);    // [64,2048] bf16 (256 KB)
    float*  u     = (float*)(Weffb + (size_t)Cdim * Edim);     // [2048] f32
    float*  beff  = u + Edim;                                  // [64] f32

    float* out = (float*)d_out;

    hipMemsetAsync(A_f32, 0, (size_t)Cdim * Edim * sizeof(float), stream);
    hipMemsetAsync(W_f32, 0, (size_t)Cdim * Edim * sizeof(float), stream);

    // A = Wmp @ Wo   (split-K x8, atomic accumulate)
    splitk_gemm_kernel<<<dim3(32, 8), 256, 0, stream>>>(Wmp, Wo, A_f32);
    // u = Wo @ bv + bo
    matvec_kernel<<<512, 256, 0, stream>>>(Wo, bv, bo, u);
    // Weff_f32 = A @ Wv
    splitk_gemm_kernel<<<dim3(32, 8), 256, 0, stream>>>(A_f32, Wv, W_f32);
    // Weffb = bf16(0.75 * Weff_f32)
    convert_kernel<<<64, 256, 0, stream>>>(W_f32, Weffb);
    // beff = 0.75 * Wmp·u + bmp
    bias2_kernel<<<64, 256, 0, stream>>>(Wmp, u, bmp, beff);
    // out = X @ Weff^T + b_eff  (+ output row permutation), split-K x4 per block
    main_gemm_kernel<<<Ntok / 16, 256, 0, stream>>>(emb, Weffb, beff, out);
}

// Round 4
// 296.540 us; speedup vs baseline: 1.5109x; 1.0398x over previous
//
#include <hip/hip_runtime.h>
#include <hip/hip_bf16.h>
#include <stdint.h>

typedef __bf16 bf16_t;
typedef __bf16 bf16x8 __attribute__((ext_vector_type(8)));
typedef __bf16 bf16x4 __attribute__((ext_vector_type(4)));
typedef float f32x4 __attribute__((ext_vector_type(4)));

#define Edim 2048
#define Cdim 64
#define Fdim 18
#define Pdim 1024
#define Ntok (Fdim * Pdim)   // 18432
#define KSPLIT 16            // k-chunks for small GEMMs

// convert 8 consecutive f32 at p (16B-aligned) to a bf16x8 fragment
__device__ __forceinline__ bf16x8 cvt8(const float* __restrict__ p) {
    float4 lo = *(const float4*)p;
    float4 hi = *(const float4*)(p + 4);
    bf16x8 r;
    r[0] = (bf16_t)lo.x; r[1] = (bf16_t)lo.y; r[2] = (bf16_t)lo.z; r[3] = (bf16_t)lo.w;
    r[4] = (bf16_t)hi.x; r[5] = (bf16_t)hi.y; r[6] = (bf16_t)hi.z; r[7] = (bf16_t)hi.w;
    return r;
}

// ---------------------------------------------------------------------------
// split-K small GEMM, no atomics: parts[ky][64][2048] = Am[64, kchunk] @ Bm[kchunk, 2048]
// grid = (32 n-tiles, 16 k-chunks of 128), block = 256 (4 waves partition M=64).
// Fully unrolled 4 k0-iters -> 128 independent B-loads in flight per wave.
// ---------------------------------------------------------------------------
template <bool A_IS_F32>
__global__ __launch_bounds__(256) void splitk_gemm_kernel(
    const void* __restrict__ Am, const float* __restrict__ Bm,
    float* __restrict__ parts)
{
    const int tid  = threadIdx.x;
    const int wave = tid >> 6;
    const int lane = tid & 63;
    const int l15  = lane & 15;
    const int koct = lane >> 4;
    const int n0   = blockIdx.x * 64;
    const int kb   = blockIdx.y * 128;

    f32x4 acc[4] = {};

    #pragma unroll
    for (int i = 0; i < 4; ++i) {
        const int k0 = kb + i * 32;
        bf16x8 a;
        if constexpr (A_IS_F32)
            a = cvt8((const float*)Am + (size_t)(wave * 16 + l15) * Edim + k0 + koct * 8);
        else
            a = *(const bf16x8*)((const bf16_t*)Am + (size_t)(wave * 16 + l15) * Edim + k0 + koct * 8);
        #pragma unroll
        for (int t = 0; t < 4; ++t) {
            const float* src = Bm + (size_t)(k0 + koct * 8) * Edim + n0 + t * 16 + l15;
            bf16x8 b;
            #pragma unroll
            for (int j = 0; j < 8; ++j) b[j] = (bf16_t)src[(size_t)j * Edim];
            acc[t] = __builtin_amdgcn_mfma_f32_16x16x32_bf16(a, b, acc[t], 0, 0, 0);
        }
    }

    float* dst = parts + (size_t)blockIdx.y * (Cdim * Edim);
    #pragma unroll
    for (int t = 0; t < 4; ++t) {
        #pragma unroll
        for (int r = 0; r < 4; ++r) {
            int m = wave * 16 + koct * 4 + r;   // C/D row = (lane>>4)*4 + reg
            int n = n0 + t * 16 + l15;          // C/D col = lane&15
            dst[(size_t)m * Edim + n] = acc[t][r];
        }
    }
}

// ---------------------------------------------------------------------------
// out_bf16[i] = scale * sum_{j<16} parts[j][i]   (131072 elems; grid 128 x 256,
// 4 elems/thread, float4 reads / bf16x4 write)
// ---------------------------------------------------------------------------
__global__ __launch_bounds__(256) void reduce_parts_kernel(
    const float* __restrict__ parts, bf16_t* __restrict__ out, float scale)
{
    const int idx = (blockIdx.x * 256 + threadIdx.x) * 4;
    float4 s = {0.f, 0.f, 0.f, 0.f};
    #pragma unroll
    for (int j = 0; j < KSPLIT; ++j) {
        float4 v = *(const float4*)(parts + (size_t)j * (Cdim * Edim) + idx);
        s.x += v.x; s.y += v.y; s.z += v.z; s.w += v.w;
    }
    bf16x4 r;
    r[0] = (bf16_t)(scale * s.x); r[1] = (bf16_t)(scale * s.y);
    r[2] = (bf16_t)(scale * s.z); r[3] = (bf16_t)(scale * s.w);
    *(bf16x4*)(out + idx) = r;
}

// ---------------------------------------------------------------------------
// u[r] = Wo[r,:]·bv + bo[r]   (grid 512 x 4 rows/block)
// ---------------------------------------------------------------------------
__global__ __launch_bounds__(256) void matvec_kernel(
    const float* __restrict__ Wo, const float* __restrict__ bv,
    const float* __restrict__ bo, float* __restrict__ u)
{
    const int tid  = threadIdx.x;
    const int wave = tid >> 6;
    const int lane = tid & 63;
    const int r    = blockIdx.x * 4 + wave;

    const float* wp = Wo + (size_t)r * Edim;
    float s = 0.f;
    #pragma unroll
    for (int c = 0; c < 8; ++c) {
        float4 w4 = *(const float4*)(wp + c * 256 + lane * 4);
        float4 b4 = *(const float4*)(bv + c * 256 + lane * 4);
        s += w4.x * b4.x + w4.y * b4.y + w4.z * b4.z + w4.w * b4.w;
    }
    #pragma unroll
    for (int off = 32; off > 0; off >>= 1) s += __shfl_down(s, off);
    if (lane == 0) u[r] = s + bo[r];
}

// ---------------------------------------------------------------------------
// b_eff[c] = 0.75 * Wmp[c,:]·u + bmp[c]    (grid 64, block 256)
// ---------------------------------------------------------------------------
__global__ __launch_bounds__(256) void bias2_kernel(
    const float* __restrict__ Wmp, const float* __restrict__ u,
    const float* __restrict__ bmp, float* __restrict__ b_eff)
{
    const int c   = blockIdx.x;
    const int tid = threadIdx.x;

    const float* wp = Wmp + (size_t)c * Edim + tid * 8;
    const float* up = u + tid * 8;
    float s = 0.f;
    #pragma unroll
    for (int j = 0; j < 8; ++j) s += wp[j] * up[j];

    #pragma unroll
    for (int off = 32; off > 0; off >>= 1) s += __shfl_down(s, off);

    __shared__ float red[4];
    if ((tid & 63) == 0) red[tid >> 6] = s;
    __syncthreads();
    if (tid == 0)
        b_eff[c] = 0.75f * (red[0] + red[1] + red[2] + red[3]) + bmp[c];
}

// ---------------------------------------------------------------------------
// main GEMM: out[(p*F+f)*64+c] = X[n,:]·Weff[c,:] + b_eff[c],  n = f*P+p
// M=32 per block (2 row-tiles per wave), split-K x4 across waves.
// grid = 576, block = 256. LDS reduce, wave 0 epilogue.
// ---------------------------------------------------------------------------
__global__ __launch_bounds__(256) void main_gemm_kernel(
    const float* __restrict__ X, const bf16_t* __restrict__ Weff,
    const float* __restrict__ b_eff, float* __restrict__ out)
{
    __shared__ float red[3 * 64 * 33];   // 3 waves x 64 lanes x 32 vals (+1 pad)

    const int tid  = threadIdx.x;
    const int wave = tid >> 6;
    const int lane = tid & 63;
    const int l15  = lane & 15;
    const int koct = lane >> 4;

    const int rbase = blockIdx.x * 32;
    const float* x0 = X + (size_t)(rbase + l15) * Edim;
    const float* x1 = x0 + (size_t)16 * Edim;
    const int kbase = wave * 512;

    f32x4 acc[2][4] = {};

    #pragma unroll 4
    for (int k0 = kbase; k0 < kbase + 512; k0 += 32) {
        bf16x8 a0 = cvt8(x0 + k0 + koct * 8);
        bf16x8 a1 = cvt8(x1 + k0 + koct * 8);
        #pragma unroll
        for (int t = 0; t < 4; ++t) {
            bf16x8 b = *(const bf16x8*)(Weff + (size_t)(t * 16 + l15) * Edim + k0 + koct * 8);
            acc[0][t] = __builtin_amdgcn_mfma_f32_16x16x32_bf16(a0, b, acc[0][t], 0, 0, 0);
            acc[1][t] = __builtin_amdgcn_mfma_f32_16x16x32_bf16(a1, b, acc[1][t], 0, 0, 0);
        }
    }

    if (wave != 0) {
        float* dst = &red[(wave - 1) * 2112 + lane * 33];
        #pragma unroll
        for (int e = 0; e < 2; ++e)
            #pragma unroll
            for (int t = 0; t < 4; ++t)
                #pragma unroll
                for (int r = 0; r < 4; ++r) dst[e * 16 + t * 4 + r] = acc[e][t][r];
    }
    __syncthreads();
    if (wave == 0) {
        #pragma unroll
        for (int w = 0; w < 3; ++w) {
            const float* srcp = &red[w * 2112 + lane * 33];
            #pragma unroll
            for (int e = 0; e < 2; ++e)
                #pragma unroll
                for (int t = 0; t < 4; ++t)
                    #pragma unroll
                    for (int r = 0; r < 4; ++r) acc[e][t][r] += srcp[e * 16 + t * 4 + r];
        }
        #pragma unroll
        for (int e = 0; e < 2; ++e) {
            const int mbase = rbase + e * 16 + koct * 4;   // C/D row base
            #pragma unroll
            for (int t = 0; t < 4; ++t) {
                const int c  = t * 16 + l15;
                const float be = b_eff[c];
                #pragma unroll
                for (int r = 0; r < 4; ++r) {
                    const int m = mbase + r;
                    const int f = m >> 10;          // n / 1024
                    const int p = m & 1023;         // n % 1024
                    out[(size_t)(p * Fdim + f) * Cdim + c] = acc[e][t][r] + be;
                }
            }
        }
    }
}

// ---------------------------------------------------------------------------
extern "C" void kernel_launch(void* const* d_in, const int* in_sizes, int n_in,
                              void* d_out, int out_size, void* d_ws, size_t ws_size,
                              hipStream_t stream)
{
    // setup_inputs order: emb, Wq, Wk, Wv, bq, bk, bv, Wo, bo, Wmp, bmp (all f32)
    const float* emb = (const float*)d_in[0];
    const float* Wv  = (const float*)d_in[3];
    const float* bv  = (const float*)d_in[6];
    const float* Wo  = (const float*)d_in[7];
    const float* bo  = (const float*)d_in[8];
    const float* Wmp = (const float*)d_in[9];
    const float* bmp = (const float*)d_in[10];

    const size_t PART = (size_t)Cdim * Edim;                 // 131072
    float*  parts1 = (float*)d_ws;                           // [16][64][2048] f32 (8 MB)
    float*  parts2 = parts1 + (size_t)KSPLIT * PART;         // 8 MB
    bf16_t* A_bf   = (bf16_t*)(parts2 + (size_t)KSPLIT * PART);  // [64,2048] bf16
    bf16_t* Weffb  = A_bf + PART;                            // [64,2048] bf16
    float*  u      = (float*)(Weffb + PART);                 // [2048] f32
    float*  beff   = u + Edim;                               // [64] f32

    float* out = (float*)d_out;

    // u = Wo @ bv + bo ; beff = 0.75 * Wmp·u + bmp
    matvec_kernel<<<512, 256, 0, stream>>>(Wo, bv, bo, u);
    bias2_kernel<<<64, 256, 0, stream>>>(Wmp, u, bmp, beff);
    // A = bf16(Wmp @ Wo)
    splitk_gemm_kernel<true><<<dim3(32, KSPLIT), 256, 0, stream>>>(Wmp, Wo, parts1);
    reduce_parts_kernel<<<128, 256, 0, stream>>>(parts1, A_bf, 1.0f);
    // Weff = bf16(0.75 * A @ Wv)
    splitk_gemm_kernel<false><<<dim3(32, KSPLIT), 256, 0, stream>>>(A_bf, Wv, parts2);
    reduce_parts_kernel<<<128, 256, 0, stream>>>(parts2, Weffb, 0.75f);
    // out = X @ Weff^T + b_eff  (+ output row permutation)
    main_gemm_kernel<<<Ntok / 32, 256, 0, stream>>>(emb, Weffb, beff, out);
}